// Round 9
// baseline (459.887 us; speedup 1.0000x reference)
//
#include <hip/hip_runtime.h>
#include <stdint.h>

typedef unsigned long long u64;
typedef unsigned int u32;
typedef unsigned short u16;

#define NN 2048
#define NW 32     // u64 words per 2048-bit row
#define NB 256    // grid blocks (co-resident: 16 waves/block, <=128 VGPR, 40KB LDS)

#if __has_builtin(__builtin_amdgcn_sbfe)
#define SBFE(x, o) ((u32)__builtin_amdgcn_sbfe((int)(x), (u32)(o), 1u))
#else
#define SBFE(x, o) ((u32)(-(int)(((x) >> (o)) & 1u)))
#endif

static __device__ __forceinline__ bool gumbel_gt(float x, float g0, float g1) {
    // jax.nn.log_sigmoid(x) = -(max(-x,0) + log1p(exp(-|x|)))
    float L = log1pf(expf(-fabsf(x)));
    float a = (-(fmaxf(-x, 0.f) + L)) + g0;   // ye[0]
    float b = (-(fmaxf( x, 0.f) + L)) + g1;   // ye[1]
    return a > b;
}

// acc |= (bit b0 of m ? w0 : 0) | (bit b0+1 of m ? w1 : 0); b0 even, compile-time
static __device__ __forceinline__ u64 orsel2(u64 acc, u64 w0, u64 w1, u64 m, int b0) {
    u32 mm = (b0 < 32) ? (u32)m : (u32)(m >> 32);
    int sh = b0 & 31;
    u32 s0 = SBFE(mm, sh);
    u32 s1 = SBFE(mm, sh + 1);
    u32 al = (u32)acc | ((u32)w0 & s0) | ((u32)w1 & s1);
    u32 ah = (u32)(acc >> 32) | ((u32)(w0 >> 32) & s0) | ((u32)(w1 >> 32) & s1);
    return ((u64)ah << 32) | al;
}

// device-scope grid barrier; one fresh counter per barrier instance (memset to 0
// before launch). All NB blocks call it the same number of times in the same order.
static __device__ __forceinline__ void gsync(u32* ctr) {
    __syncthreads();
    if (threadIdx.x == 0) {
        __threadfence();   // release: flush this block's stores to device scope
        __hip_atomic_fetch_add(ctr, 1u, __ATOMIC_ACQ_REL, __HIP_MEMORY_SCOPE_AGENT);
        while (__hip_atomic_load(ctr, __ATOMIC_ACQUIRE, __HIP_MEMORY_SCOPE_AGENT) < (u32)NB) {}
        __threadfence();   // acquire: invalidate stale lines before reading others' data
    }
    __syncthreads();
}

// ---------------------------------------------------------------------------
// order body (proven round-8 code, LDS via smem union). Runs on block 0 only.
// ---------------------------------------------------------------------------
static __device__ void order_body(char* smem,
    const float* __restrict__ root_logits, const float* __restrict__ g_root,
    const u64* __restrict__ heBits,
    u16* __restrict__ posr, u16* __restrict__ porderW, int* __restrict__ nrPtr)
{
    int* s_porder = (int*)smem;                    // 8192
    int* s_cnt    = (int*)(smem + 8192);           // 8192
    u64 (*s_U)[NW]  = (u64(*)[NW])(smem + 16384);  // 4096
    u64 (*s_Pg)[NW] = (u64(*)[NW])(smem + 20480);  // 4096
    u16* s_pos = (u16*)(smem + 24576);             // 4096
    u16* s_f   = (u16*)(smem + 28672);             // 4096
    u16* s_rk  = (u16*)(smem + 32768);             // 4096
    u64* s_root = (u64*)(smem + 36864);            // 256
    u64* s_enq  = (u64*)(smem + 37120);            // 256
    u64* s_F    = (u64*)(smem + 37376);            // 256
    int* s_wsum = (int*)(smem + 37632);            // 64
    int* s_woff = (int*)(smem + 37696);            // 64
    int* s_sc   = (int*)(smem + 37760);            // scalars
    int &s_base = s_sc[0]; int &s_lo = s_sc[1]; int &s_levcnt = s_sc[2];
    int &s_newcnt = s_sc[3]; int &s_nr = s_sc[4];

    const int t    = threadIdx.x;
    const int lane = t & 63;
    const int wid  = t >> 6;
    const int half = lane >> 5;
    const int w    = lane & 31;

    for (int p = 0; p < 2; ++p) {
        int j = p * 1024 + t;
        bool rb = gumbel_gt(root_logits[j], g_root[j], g_root[NN + j]);
        u64 m = __ballot(rb);
        if (lane == 0) s_root[j >> 6] = m;
    }
    __syncthreads();
    for (int p = 0; p < 2; ++p) {
        int j = p * 1024 + t;
        int ww = j >> 6; u64 bit = 1ull << (j & 63);
        if (s_root[ww] & bit) {
            int r = 0;
            for (int k = 0; k < ww; ++k) r += __popcll(s_root[k]);
            r += __popcll(s_root[ww] & (bit - 1ull));
            s_pos[j] = (u16)r;
            s_porder[r] = j;
        }
    }
    if (t < NW) s_enq[t] = s_root[t];
    if (t == 0) {
        int tl = 0;
        for (int k = 0; k < NW; ++k) tl += __popcll(s_root[k]);
        s_lo = 0; s_levcnt = tl; s_base = tl; s_nr = tl;
    }
    __syncthreads();

    while (s_levcnt > 0 && s_base < NN) {
        const int lo = s_lo, cnt = s_levcnt, base = s_base;
        const int seglen = (cnt + 15) >> 4;
        const int s0 = wid * seglen;
        const int s1 = (s0 + seglen < cnt) ? (s0 + seglen) : cnt;

        {
            u64 acc = 0;
            for (int m = s0 + half; m < s1; m += 2)
                acc |= heBits[(size_t)s_porder[lo + m] * NW + w];
            acc |= __shfl(acc, lane ^ 32);
            if (half == 0) s_U[wid][w] = acc;
        }
        __syncthreads();
        if (t < NW) {
            u64 o = 0;
            #pragma unroll
            for (int s = 0; s < 16; ++s) o |= s_U[s][t];
            s_F[t] = o & ~s_enq[t] & ~s_root[t];
        }
        __syncthreads();
        if (t < 512) {
            int s = t >> 5, ww = t & 31;
            u64 p = 0;
            for (int s2 = 0; s2 < s; ++s2) p |= s_U[s2][ww];
            s_Pg[s][ww] = p & s_F[ww];
        }
        __syncthreads();
        {
            u64 P  = s_Pg[wid][w];
            u64 Fw = s_F[w];
            int myidx = (s0 + lane < s1) ? s_porder[lo + s0 + lane] : 0;
            u64 rnext = 0;
            {
                int rowi0 = __shfl(myidx, half);
                if (s0 + half < s1) rnext = heBits[(size_t)rowi0 * NW + w];
            }
            for (int m = s0; m < s1; m += 2) {
                int m0 = m + half;
                u64 r = rnext;
                {
                    int sidx = (m + 2 - s0) + half;
                    if (sidx > 63) sidx = 0;
                    int rowin = __shfl(myidx, sidx);
                    rnext = 0;
                    if (m + 2 + half < s1) rnext = heBits[(size_t)rowin * NW + w];
                }
                u64 v = (m0 < s1) ? (r & Fw & ~P) : 0ull;
                u64 vlo = __shfl(v, w);
                u64 B = half ? (v & ~vlo) : v;
                int pc = __popcll(B);
                int inc = pc;
                #pragma unroll
                for (int d = 1; d < 32; d <<= 1) {
                    int u2 = __shfl_up(inc, d, 64);
                    if (w >= d) inc += u2;
                }
                int excl = inc - pc;
                int tot = __shfl(inc, (half << 5) | 31);
                if (w == 0 && m0 < s1) s_cnt[m0] = tot;
                u64 mm = B;
                int idx = excl;
                while (mm) {
                    int b = __ffsll(mm) - 1; mm &= mm - 1;
                    int j = (w << 6) + b;
                    s_f[j]  = (u16)m0;
                    s_rk[j] = (u16)idx++;
                }
                P |= B | __shfl(B, lane ^ 32);
            }
        }
        __syncthreads();
        {
            int b0 = 2 * t, b1 = 2 * t + 1;
            int c0 = (b0 < cnt) ? s_cnt[b0] : 0;
            int c1 = (b1 < cnt) ? s_cnt[b1] : 0;
            int pairv = c0 + c1;
            int incl = pairv;
            for (int d = 1; d < 64; d <<= 1) {
                int v = __shfl_up(incl, d, 64);
                if (lane >= d) incl += v;
            }
            if (lane == 63) s_wsum[wid] = incl;
            __syncthreads();
            if (t < 16) {
                int v = s_wsum[t];
                int inc2 = v;
                for (int d = 1; d < 16; d <<= 1) {
                    int u = __shfl_up(inc2, d, 16);
                    if (t >= d) inc2 += u;
                }
                s_woff[t] = inc2 - v;
                if (t == 15) s_newcnt = inc2;
            }
            __syncthreads();
            int excl = s_woff[wid] + (incl - pairv);
            if (b0 < cnt) s_cnt[b0] = excl;
            if (b1 < cnt) s_cnt[b1] = excl + c0;
        }
        __syncthreads();
        for (int p = 0; p < 2; ++p) {
            int j = p * 1024 + t;
            int ww = j >> 6;
            if ((s_F[ww] >> (j & 63)) & 1ull) {
                int slot = base + s_cnt[s_f[j]] + s_rk[j];
                s_pos[j] = (u16)slot;
                s_porder[slot] = j;
            }
        }
        if (t < NW) s_enq[t] |= s_F[t];
        __syncthreads();
        if (t == 0) { s_lo = base; s_levcnt = s_newcnt; s_base = base + s_newcnt; }
        __syncthreads();
    }

    for (int p = 0; p < 2; ++p) {
        int j = p * 1024 + t;
        int ww = j >> 6; u64 bit = 1ull << (j & 63);
        if (!((s_enq[ww] >> (j & 63)) & 1ull)) {
            int rk = 0;
            for (int k2 = 0; k2 < ww; ++k2) rk += __popcll(~s_enq[k2]);
            rk += __popcll(~s_enq[ww] & (bit - 1ull));
            int slot = s_base + rk;
            s_pos[j] = (u16)slot;
            s_porder[slot] = j;
        }
    }
    __syncthreads();
    for (int p = 0; p < 2; ++p) {
        int j = p * 1024 + t;
        int fl = s_pos[j];
        if ((s_root[j >> 6] >> (j & 63)) & 1ull) fl |= 0x8000;
        if ((s_enq[j >> 6]  >> (j & 63)) & 1ull) fl |= 0x4000;
        posr[j] = (u16)fl;
        porderW[j] = (u16)s_porder[j];
    }
    if (t == 0) *nrPtr = s_nr;
}

// ---------------------------------------------------------------------------
// merge body (proven round-7/8 no-atomic matmul), adapted: all 1024 threads
// stage SQ; threads 0..255 compute. Call under uniform per-block guard.
// ---------------------------------------------------------------------------
static __device__ void merge_body(char* smem, int rb,
    const u64* __restrict__ Pb, int pstr,
    const u64* __restrict__ Qb, int qstr,
    u64* __restrict__ Ob, int ostr)
{
    u64 (*SQ)[17] = (u64(*)[17])smem;             // 34816 B
    u64 (*PL)[16] = (u64(*)[16])(smem + 34816);   //  2048 B
    const int t    = threadIdx.x;
    const int lane = t & 63;
    const int grp  = lane >> 4;
    const int w    = lane & 15;

    if (t < 256) PL[t >> 4][t & 15] = Pb[(size_t)(16 * rb + (t >> 4)) * pstr + (t & 15)];

    u64 acc0 = 0, acc1 = 0, acc2 = 0, acc3 = 0;

    for (int cs = 0; cs < 4; ++cs) {
        __syncthreads();
        for (int q = t; q < 4096; q += 1024)
            SQ[q >> 4][q & 15] = Qb[(size_t)(256 * cs + (q >> 4)) * qstr + (q & 15)];
        __syncthreads();
        if (t < 256) {
            const int wvv = t >> 6;
            #pragma unroll
            for (int cw = 0; cw < 4; ++cw) {
                u64 m0 = PL[4 * wvv + 0][cs * 4 + cw];
                u64 m1 = PL[4 * wvv + 1][cs * 4 + cw];
                u64 m2 = PL[4 * wvv + 2][cs * 4 + cw];
                u64 m3 = PL[4 * wvv + 3][cs * 4 + cw];
                #pragma unroll
                for (int cc = 0; cc < 16; ++cc) {
                    u64 qq = SQ[cw * 64 + cc * 4 + grp][w];
                    int sh = (cc & 7) * 4 + grp;
                    u32 h0 = (cc < 8) ? (u32)m0 : (u32)(m0 >> 32);
                    u32 h1 = (cc < 8) ? (u32)m1 : (u32)(m1 >> 32);
                    u32 h2 = (cc < 8) ? (u32)m2 : (u32)(m2 >> 32);
                    u32 h3 = (cc < 8) ? (u32)m3 : (u32)(m3 >> 32);
                    u32 ql = (u32)qq, qh = (u32)(qq >> 32);
                    u32 s;
                    s = SBFE(h0, sh);
                    acc0 = ((u64)(((u32)(acc0 >> 32)) | (qh & s)) << 32) | (((u32)acc0) | (ql & s));
                    s = SBFE(h1, sh);
                    acc1 = ((u64)(((u32)(acc1 >> 32)) | (qh & s)) << 32) | (((u32)acc1) | (ql & s));
                    s = SBFE(h2, sh);
                    acc2 = ((u64)(((u32)(acc2 >> 32)) | (qh & s)) << 32) | (((u32)acc2) | (ql & s));
                    s = SBFE(h3, sh);
                    acc3 = ((u64)(((u32)(acc3 >> 32)) | (qh & s)) << 32) | (((u32)acc3) | (ql & s));
                }
            }
        }
    }

    if (t < 256) {
        const int wvv = t >> 6;
        acc0 |= __shfl_xor(acc0, 16); acc0 |= __shfl_xor(acc0, 32);
        acc1 |= __shfl_xor(acc1, 16); acc1 |= __shfl_xor(acc1, 32);
        acc2 |= __shfl_xor(acc2, 16); acc2 |= __shfl_xor(acc2, 32);
        acc3 |= __shfl_xor(acc3, 16); acc3 |= __shfl_xor(acc3, 32);
        if (grp == 0) {
            size_t base = (size_t)(16 * rb + 4 * wvv) * ostr + w;
            Ob[base] = acc0;
            Ob[base + ostr] = acc1;
            Ob[base + 2 * (size_t)ostr] = acc2;
            Ob[base + 3 * (size_t)ostr] = acc3;
        }
    }
}

// ---------------------------------------------------------------------------
// THE mega kernel: all phases, one launch, hand-rolled grid barriers.
// ---------------------------------------------------------------------------
__global__ __launch_bounds__(1024, 4) void mega_kernel(
    const float* __restrict__ root_logits,
    const float* __restrict__ edge_logits,
    const float* __restrict__ g_root,
    const float* __restrict__ g_edge,
    u64* __restrict__ heBits, u64* __restrict__ heT,
    u64* __restrict__ Ap, u64* __restrict__ Anc,
    u64* __restrict__ Di, u64* __restrict__ M1,
    u16* __restrict__ posr, u16* __restrict__ porderW, int* __restrict__ nrPtr,
    u32* __restrict__ ctrs,
    float* __restrict__ dag)
{
    __shared__ __align__(16) char smem[40960];
    const int bid  = blockIdx.x;
    const int t    = threadIdx.x;
    const int lane = t & 63;
    const int wv   = t >> 6;

    // ---- P0: prep — he bitmask, 8 rows per block ----
    for (int r = 0; r < 8; ++r) {
        const int i = 8 * bid + r;
        {
            int j = t;
            float x  = edge_logits[(size_t)i * NN + j];
            float g0 = g_edge[(size_t)i * (2 * NN) + j];
            float g1 = g_edge[(size_t)i * (2 * NN) + NN + j];
            u64 m = __ballot(gumbel_gt(x, g0, g1));
            if (lane == 0) heBits[(size_t)i * NW + wv] = m;
        }
        {
            int j = t + 1024;
            float x  = edge_logits[(size_t)i * NN + j];
            float g0 = g_edge[(size_t)i * (2 * NN) + j];
            float g1 = g_edge[(size_t)i * (2 * NN) + NN + j];
            u64 m = __ballot(gumbel_gt(x, g0, g1));
            if (lane == 0) heBits[(size_t)i * NW + 16 + wv] = m;
        }
    }
    gsync(&ctrs[0]);

    // ---- P1: order (block 0)  ||  transpose (blocks 1..255, wave per tile) ----
    if (bid == 0) {
        order_body(smem, root_logits, g_root, heBits, posr, porderW, nrPtr);
    } else {
        int gw = (bid - 1) * 16 + wv;
        if (gw < 1024) {
            int ti = gw >> 5, tj = gw & 31;
            u64 w = heBits[(size_t)(64 * ti + lane) * NW + tj];
            u64 out = 0;
            #pragma unroll
            for (int b = 0; b < 64; ++b) {
                u64 m = __ballot(((w >> b) & 1ull) != 0);
                if (b == lane) out = m;
            }
            heT[(size_t)(64 * tj + lane) * NW + ti] = out;
        }
    }
    gsync(&ctrs[1]);

    // ---- P2: apbuild — wave per permuted row b ----
    {
        u16* s_inv = (u16*)smem;   // 4 KB
        s_inv[t] = porderW[t];
        s_inv[t + 1024] = porderW[t + 1024];
        __syncthreads();
        if (wv < 8) {
            const int b = 8 * bid + wv;
            const int nr = *nrPtr;
            const bool bge = (b >= nr);
            const int invb = s_inv[b];
            u64 rw = 0;
            if (lane < 32) rw = heT[(size_t)invb * NW + lane];
            for (int k = 0; k < 32; ++k) {
                int a = 64 * k + lane;
                int ia = s_inv[a];
                u64 wword = __shfl(rw, ia >> 6);
                bool bit = bge && (a < b) && (((wword >> (ia & 63)) & 1ull) != 0);
                u64 m = __ballot(bit);
                if (lane == 0) Ap[(size_t)b * NW + k] = m;
            }
        }
    }
    gsync(&ctrs[2]);

    // ---- P3: diag closure + premultiply — wave per (i,j) pair, shuffle-based ----
    {
        int p = wv * 256 + bid;
        if (p < 528) {
            int i = 0;
            while ((i + 1) * (i + 2) / 2 <= p) ++i;
            int j = p - i * (i + 1) / 2;
            u64 M = Ap[(size_t)(64 * i + lane) * NW + i] | (1ull << lane);
            for (int s = 0; s < 6; ++s) {
                u64 acc = 0;
                for (int b = 0; b < 64; ++b)
                    acc |= __shfl(M, b) & (0ull - ((M >> b) & 1ull));
                M = acc;
            }
            if (j == i) {
                Di[64 * i + lane] = M;
            } else {
                u64 X = Ap[(size_t)(64 * i + lane) * NW + j];
                u64 acc = 0;
                for (int b = 0; b < 64; ++b)
                    acc |= __shfl(X, b) & (0ull - ((M >> b) & 1ull));
                Ap[(size_t)(64 * i + lane) * NW + j] = acc;
            }
        }
    }
    gsync(&ctrs[3]);

    // ---- P4: colhalf — blocks 0..31, one per column ----
    if (bid < 32) {
        u64 (*colA)[64] = (u64(*)[64])smem;          // 8 KB
        u64 (*part)[64] = (u64(*)[64])(smem + 8192); // 8 KB
        const int r  = lane;
        const int k    = bid & 15;
        const int hb   = bid >> 4;
        const int base = hb << 4;
        const int bend = base + 16;
        const int kk   = base + k;

        for (int row = t; row < 64 * kk; row += 1024)
            Anc[(size_t)row * NW + kk] = 0ull;

        if (t < 64) {
            u64 d = Di[64 * kk + r];
            colA[0][r] = d;
            Anc[(size_t)(64 * kk + r) * NW + kk] = d;
        }
        __syncthreads();

        const int j0 = kk + wv;

        for (int ib = kk + 1; ib < bend; ib += 4) {
            u64 m0[4], acc[4];
            #pragma unroll
            for (int g = 0; g < 4; ++g) {
                int ig = ib + g;
                bool v = (ig < bend);
                m0[g] = (v && (j0 < ib)) ? Ap[(size_t)(64 * ig + r) * NW + j0] : 0ull;
                acc[g] = 0ull;
            }
            u64 tm[3][3];
            #pragma unroll
            for (int s = 0; s < 3; ++s) {
                #pragma unroll
                for (int q = 0; q < 3; ++q) {
                    int g = s + 1 + q;
                    tm[s][q] = (g < 4 && (ib + g) < bend)
                        ? Ap[(size_t)(64 * (ib + g) + r) * NW + (ib + s)] : 0ull;
                }
            }

            if (j0 < ib) {
                const ulonglong2* rp = (const ulonglong2*)&colA[j0 - kk][0];
                #pragma unroll
                for (int bp = 0; bp < 32; ++bp) {
                    ulonglong2 ww = rp[bp];
                    #pragma unroll
                    for (int g = 0; g < 4; ++g)
                        acc[g] = orsel2(acc[g], ww.x, ww.y, m0[g], 2 * bp);
                }
            }

            #pragma unroll
            for (int s = 0; s < 4; ++s) {
                const int i = ib + s;
                if (i < bend) {
                    part[wv][r] = acc[s];
                    __syncthreads();
                    if (wv < 2) {
                        u64 red = part[0][r];
                        #pragma unroll
                        for (int p = 1; p < 16; ++p) red |= part[p][r];
                        if (wv == 0) colA[i - kk][r] = red;
                        else Anc[(size_t)(64 * i + r) * NW + kk] = red;
                    }
                    __syncthreads();
                    if (s < 3 && (i + 1) < bend) {
                        const u64* rowp = colA[i - kk];
                        #pragma unroll
                        for (int bi = 0; bi < 4; ++bi) {
                            int b = 4 * wv + bi;
                            u64 w = rowp[b];
                            u32 wl = (u32)w, wh = (u32)(w >> 32);
                            #pragma unroll
                            for (int q = 0; q < 3; ++q) {
                                int g = s + 1 + q;
                                if (g < 4) {
                                    u32 sm2 = (u32)(0u - (u32)((tm[s][q] >> b) & 1ull));
                                    u32 al = (u32)acc[g] | (wl & sm2);
                                    u32 ah = (u32)(acc[g] >> 32) | (wh & sm2);
                                    acc[g] = ((u64)ah << 32) | al;
                                }
                            }
                        }
                    }
                }
            }
        }
    }
    gsync(&ctrs[4]);

    // ---- P5: merge1 — M1 = C' * A*  (blocks 0..63) ----
    if (bid < 64)
        merge_body(smem, bid, Ap + (size_t)1024 * NW, NW, Anc, NW, M1, 16);
    gsync(&ctrs[5]);

    // ---- P6: merge2 — Anc[B, T-words] = B* * M1  (blocks 0..63) ----
    if (bid < 64)
        merge_body(smem, bid, Anc + (size_t)1024 * NW + 16, NW, M1, 16,
                   Anc + (size_t)1024 * NW, NW);
    gsync(&ctrs[6]);

    // ---- P7: foldout — 8 rows per block ----
    {
        u16* s_pr  = (u16*)smem;            // 4 KB
        u64* s_anc = (u64*)(smem + 4096);   // 256 B
        u64* s_he  = (u64*)(smem + 4352);   // 256 B
        if (t < 256) ((int4*)s_pr)[t] = ((const int4*)posr)[t];
        __syncthreads();
        for (int r = 0; r < 8; ++r) {
            const int i = 8 * bid + r;
            const int fl = s_pr[i];
            const int pi = fl & 0x7FF;
            if (t < 32) {
                s_anc[t] = Anc[(size_t)pi * NW + t];
                s_he[t]  = heBits[(size_t)i * NW + t];
            }
            __syncthreads();
            const bool reach_i = (fl & 0x4000) != 0;
            const int j = 2 * t;
            int pr0 = s_pr[j], pr1 = s_pr[j + 1];
            int a0 = pr0 & 0x7FF, a1 = pr1 & 0x7FF;
            u64 hw = s_he[j >> 6];
            bool he0 = ((hw >> (j & 63)) & 1ull) != 0;
            bool he1 = ((hw >> ((j + 1) & 63)) & 1ull) != 0;
            bool an0 = ((s_anc[a0 >> 6] >> (a0 & 63)) & 1ull) != 0;
            bool an1 = ((s_anc[a1 >> 6] >> (a1 & 63)) & 1ull) != 0;
            float o0 = (reach_i && he0 && ((pr0 & 0x8000) == 0) && !an0) ? 1.f : 0.f;
            float o1 = (reach_i && he1 && ((pr1 & 0x8000) == 0) && !an1) ? 1.f : 0.f;
            ((float2*)(dag + (size_t)i * NN))[t] = make_float2(o0, o1);
            __syncthreads();
        }
    }
}

// ---------------------------------------------------------------------------
extern "C" void kernel_launch(void* const* d_in, const int* in_sizes, int n_in,
                              void* d_out, int out_size, void* d_ws, size_t ws_size,
                              hipStream_t stream) {
    const float* root_logits = (const float*)d_in[0];
    const float* edge_logits = (const float*)d_in[1];
    const float* g_root      = (const float*)d_in[2];
    const float* g_edge      = (const float*)d_in[3];
    float* dag = (float*)d_out;

    char* ws = (char*)d_ws;
    u64* heBits  = (u64*)(ws);                            // 512 KB
    u64* heT     = (u64*)(ws + (512 << 10));              // 512 KB
    u64* Ap      = (u64*)(ws + (1 << 20));                // 512 KB
    u64* Anc     = (u64*)(ws + (1 << 20) + (512 << 10));  // 512 KB
    u64* Di      = (u64*)(ws + (2 << 20));                //  16 KB
    u64* M1      = (u64*)(ws + (2 << 20) + (64 << 10));   // 128 KB
    u16* posr    = (u16*)(ws + (2 << 20) + (192 << 10));  //   4 KB
    u16* porderW = (u16*)(ws + (2 << 20) + (196 << 10));  //   4 KB
    int* nrPtr   = (int*)(ws + (2 << 20) + (200 << 10));  //   4 B
    u32* ctrs    = (u32*)(ws + (2 << 20) + (256 << 10));  //  64 B (barrier counters)

    hipMemsetAsync(ctrs, 0, 64, stream);
    mega_kernel<<<NB, 1024, 0, stream>>>(root_logits, edge_logits, g_root, g_edge,
                                         heBits, heT, Ap, Anc, Di, M1,
                                         posr, porderW, nrPtr, ctrs, dag);
}

// Round 10
// 154.462 us; speedup vs baseline: 2.9773x; 2.9773x over previous
//
#include <hip/hip_runtime.h>
#include <stdint.h>

typedef unsigned long long u64;
typedef unsigned int u32;
typedef unsigned short u16;

#define NN 2048
#define NW 32    // u64 words per 2048-bit row

#if __has_builtin(__builtin_amdgcn_sbfe)
#define SBFE(x, o) ((u32)__builtin_amdgcn_sbfe((int)(x), (u32)(o), 1u))
#else
#define SBFE(x, o) ((u32)(-(int)(((x) >> (o)) & 1u)))
#endif

static __device__ __forceinline__ bool gumbel_gt(float x, float g0, float g1) {
    // jax.nn.log_sigmoid(x) = -(max(-x,0) + log1p(exp(-|x|)))
    float L = log1pf(expf(-fabsf(x)));
    float a = (-(fmaxf(-x, 0.f) + L)) + g0;   // ye[0]
    float b = (-(fmaxf( x, 0.f) + L)) + g1;   // ye[1]
    return a > b;
}

// acc |= (bit b0 of m ? w0 : 0) | (bit b0+1 of m ? w1 : 0); b0 even, compile-time
static __device__ __forceinline__ u64 orsel2(u64 acc, u64 w0, u64 w1, u64 m, int b0) {
    u32 mm = (b0 < 32) ? (u32)m : (u32)(m >> 32);
    int sh = b0 & 31;
    u32 s0 = SBFE(mm, sh);
    u32 s1 = SBFE(mm, sh + 1);
    u32 al = (u32)acc | ((u32)w0 & s0) | ((u32)w1 & s1);
    u32 ah = (u32)(acc >> 32) | ((u32)(w0 >> 32) & s0) | ((u32)(w1 >> 32) & s1);
    return ((u64)ah << 32) | al;
}

// ---------------------------------------------------------------------------
// K1: hard-edge bitmask  he[i][j]  (round-8 proven)
// ---------------------------------------------------------------------------
__global__ __launch_bounds__(256) void prep_kernel(
    const float* __restrict__ edge_logits,
    const float* __restrict__ g_edge,
    u64* __restrict__ heBits)
{
    const int i = blockIdx.x;
    const int t = threadIdx.x;
    const int lane = t & 63;
    const int wave = t >> 6;
    for (int c = wave; c < NW; c += 4) {
        int j = (c << 6) + lane;
        float x  = edge_logits[(size_t)i * NN + j];
        float g0 = g_edge[(size_t)i * (2 * NN) + j];
        float g1 = g_edge[(size_t)i * (2 * NN) + NN + j];
        u64 m = __ballot(gumbel_gt(x, g0, g1));
        if (lane == 0) heBits[(size_t)i * NW + c] = m;
    }
}

// ---------------------------------------------------------------------------
// order body (round-8 proven code; LDS via smem pointer — validated in mega).
// ---------------------------------------------------------------------------
static __device__ void order_body(char* smem,
    const float* __restrict__ root_logits, const float* __restrict__ g_root,
    const u64* __restrict__ heBits,
    u16* __restrict__ posr, u16* __restrict__ porderW, int* __restrict__ nrPtr)
{
    int* s_porder = (int*)smem;                    // 8192
    int* s_cnt    = (int*)(smem + 8192);           // 8192
    u64 (*s_U)[NW]  = (u64(*)[NW])(smem + 16384);  // 4096
    u64 (*s_Pg)[NW] = (u64(*)[NW])(smem + 20480);  // 4096
    u16* s_pos = (u16*)(smem + 24576);             // 4096
    u16* s_f   = (u16*)(smem + 28672);             // 4096
    u16* s_rk  = (u16*)(smem + 32768);             // 4096
    u64* s_root = (u64*)(smem + 36864);            // 256
    u64* s_enq  = (u64*)(smem + 37120);            // 256
    u64* s_F    = (u64*)(smem + 37376);            // 256
    int* s_wsum = (int*)(smem + 37632);            // 64
    int* s_woff = (int*)(smem + 37696);            // 64
    int* s_sc   = (int*)(smem + 37760);            // scalars
    int &s_base = s_sc[0]; int &s_lo = s_sc[1]; int &s_levcnt = s_sc[2];
    int &s_newcnt = s_sc[3]; int &s_nr = s_sc[4];

    const int t    = threadIdx.x;
    const int lane = t & 63;
    const int wid  = t >> 6;
    const int half = lane >> 5;
    const int w    = lane & 31;

    for (int p = 0; p < 2; ++p) {
        int j = p * 1024 + t;
        bool rb = gumbel_gt(root_logits[j], g_root[j], g_root[NN + j]);
        u64 m = __ballot(rb);
        if (lane == 0) s_root[j >> 6] = m;
    }
    __syncthreads();
    for (int p = 0; p < 2; ++p) {
        int j = p * 1024 + t;
        int ww = j >> 6; u64 bit = 1ull << (j & 63);
        if (s_root[ww] & bit) {
            int r = 0;
            for (int k = 0; k < ww; ++k) r += __popcll(s_root[k]);
            r += __popcll(s_root[ww] & (bit - 1ull));
            s_pos[j] = (u16)r;
            s_porder[r] = j;
        }
    }
    if (t < NW) s_enq[t] = s_root[t];
    if (t == 0) {
        int tl = 0;
        for (int k = 0; k < NW; ++k) tl += __popcll(s_root[k]);
        s_lo = 0; s_levcnt = tl; s_base = tl; s_nr = tl;
    }
    __syncthreads();

    while (s_levcnt > 0 && s_base < NN) {
        const int lo = s_lo, cnt = s_levcnt, base = s_base;
        const int seglen = (cnt + 15) >> 4;
        const int s0 = wid * seglen;
        const int s1 = (s0 + seglen < cnt) ? (s0 + seglen) : cnt;

        {
            u64 acc = 0;
            for (int m = s0 + half; m < s1; m += 2)
                acc |= heBits[(size_t)s_porder[lo + m] * NW + w];
            acc |= __shfl(acc, lane ^ 32);
            if (half == 0) s_U[wid][w] = acc;
        }
        __syncthreads();
        if (t < NW) {
            u64 o = 0;
            #pragma unroll
            for (int s = 0; s < 16; ++s) o |= s_U[s][t];
            s_F[t] = o & ~s_enq[t] & ~s_root[t];
        }
        __syncthreads();
        if (t < 512) {
            int s = t >> 5, ww = t & 31;
            u64 p = 0;
            for (int s2 = 0; s2 < s; ++s2) p |= s_U[s2][ww];
            s_Pg[s][ww] = p & s_F[ww];
        }
        __syncthreads();
        {
            u64 P  = s_Pg[wid][w];
            u64 Fw = s_F[w];
            int myidx = (s0 + lane < s1) ? s_porder[lo + s0 + lane] : 0;
            u64 rnext = 0;
            {
                int rowi0 = __shfl(myidx, half);
                if (s0 + half < s1) rnext = heBits[(size_t)rowi0 * NW + w];
            }
            for (int m = s0; m < s1; m += 2) {
                int m0 = m + half;
                u64 r = rnext;
                {
                    int sidx = (m + 2 - s0) + half;
                    if (sidx > 63) sidx = 0;
                    int rowin = __shfl(myidx, sidx);
                    rnext = 0;
                    if (m + 2 + half < s1) rnext = heBits[(size_t)rowin * NW + w];
                }
                u64 v = (m0 < s1) ? (r & Fw & ~P) : 0ull;
                u64 vlo = __shfl(v, w);
                u64 B = half ? (v & ~vlo) : v;
                int pc = __popcll(B);
                int inc = pc;
                #pragma unroll
                for (int d = 1; d < 32; d <<= 1) {
                    int u2 = __shfl_up(inc, d, 64);
                    if (w >= d) inc += u2;
                }
                int excl = inc - pc;
                int tot = __shfl(inc, (half << 5) | 31);
                if (w == 0 && m0 < s1) s_cnt[m0] = tot;
                u64 mm = B;
                int idx = excl;
                while (mm) {
                    int b = __ffsll(mm) - 1; mm &= mm - 1;
                    int j = (w << 6) + b;
                    s_f[j]  = (u16)m0;
                    s_rk[j] = (u16)idx++;
                }
                P |= B | __shfl(B, lane ^ 32);
            }
        }
        __syncthreads();
        {
            int b0 = 2 * t, b1 = 2 * t + 1;
            int c0 = (b0 < cnt) ? s_cnt[b0] : 0;
            int c1 = (b1 < cnt) ? s_cnt[b1] : 0;
            int pairv = c0 + c1;
            int incl = pairv;
            for (int d = 1; d < 64; d <<= 1) {
                int v = __shfl_up(incl, d, 64);
                if (lane >= d) incl += v;
            }
            if (lane == 63) s_wsum[wid] = incl;
            __syncthreads();
            if (t < 16) {
                int v = s_wsum[t];
                int inc2 = v;
                for (int d = 1; d < 16; d <<= 1) {
                    int u = __shfl_up(inc2, d, 16);
                    if (t >= d) inc2 += u;
                }
                s_woff[t] = inc2 - v;
                if (t == 15) s_newcnt = inc2;
            }
            __syncthreads();
            int excl = s_woff[wid] + (incl - pairv);
            if (b0 < cnt) s_cnt[b0] = excl;
            if (b1 < cnt) s_cnt[b1] = excl + c0;
        }
        __syncthreads();
        for (int p = 0; p < 2; ++p) {
            int j = p * 1024 + t;
            int ww = j >> 6;
            if ((s_F[ww] >> (j & 63)) & 1ull) {
                int slot = base + s_cnt[s_f[j]] + s_rk[j];
                s_pos[j] = (u16)slot;
                s_porder[slot] = j;
            }
        }
        if (t < NW) s_enq[t] |= s_F[t];
        __syncthreads();
        if (t == 0) { s_lo = base; s_levcnt = s_newcnt; s_base = base + s_newcnt; }
        __syncthreads();
    }

    for (int p = 0; p < 2; ++p) {
        int j = p * 1024 + t;
        int ww = j >> 6; u64 bit = 1ull << (j & 63);
        if (!((s_enq[ww] >> (j & 63)) & 1ull)) {
            int rk = 0;
            for (int k2 = 0; k2 < ww; ++k2) rk += __popcll(~s_enq[k2]);
            rk += __popcll(~s_enq[ww] & (bit - 1ull));
            int slot = s_base + rk;
            s_pos[j] = (u16)slot;
            s_porder[slot] = j;
        }
    }
    __syncthreads();
    for (int p = 0; p < 2; ++p) {
        int j = p * 1024 + t;
        int fl = s_pos[j];
        if ((s_root[j >> 6] >> (j & 63)) & 1ull) fl |= 0x8000;
        if ((s_enq[j >> 6]  >> (j & 63)) & 1ull) fl |= 0x4000;
        posr[j] = (u16)fl;
        porderW[j] = (u16)s_porder[j];
    }
    if (t == 0) *nrPtr = s_nr;
}

// ---------------------------------------------------------------------------
// K2 (fused): block 0 = order; blocks 1..255 = bit-transpose (wave per tile).
// Independent outputs, both read only heBits -> no cross-block sync needed.
// (This exact structure passed validation inside round-9's mega kernel.)
// ---------------------------------------------------------------------------
__global__ __launch_bounds__(1024) void ordtrans_kernel(
    const float* __restrict__ root_logits,
    const float* __restrict__ g_root,
    const u64* __restrict__ heBits,
    u64* __restrict__ heT,
    u16* __restrict__ posr,
    u16* __restrict__ porderW,
    int* __restrict__ nrPtr)
{
    __shared__ __align__(16) char smem[38016];
    const int bid  = blockIdx.x;
    const int t    = threadIdx.x;
    const int lane = t & 63;
    const int wv   = t >> 6;

    if (bid == 0) {
        order_body(smem, root_logits, g_root, heBits, posr, porderW, nrPtr);
    } else {
        int gw = (bid - 1) * 16 + wv;
        if (gw < 1024) {
            int ti = gw >> 5, tj = gw & 31;
            u64 w = heBits[(size_t)(64 * ti + lane) * NW + tj];
            u64 out = 0;
            #pragma unroll
            for (int b = 0; b < 64; ++b) {
                u64 m = __ballot(((w >> b) & 1ull) != 0);
                if (b == lane) out = m;
            }
            heT[(size_t)(64 * tj + lane) * NW + ti] = out;
        }
    }
}

// ---------------------------------------------------------------------------
// K3: permuted strict-lower parent matrix (round-8 proven)
// ---------------------------------------------------------------------------
__global__ __launch_bounds__(256) void apbuild_kernel(
    const u64* __restrict__ heT, const u16* __restrict__ porderW,
    const int* __restrict__ nrPtr, u64* __restrict__ Ap)
{
    __shared__ u64 s_row[NW];
    __shared__ u16 s_inv[NN];
    __shared__ int s_invb, s_nr;
    const int b = blockIdx.x;
    const int t = threadIdx.x;
    for (int q = t; q < NN; q += 256) s_inv[q] = porderW[q];
    if (t == 0) { s_invb = porderW[b]; s_nr = *nrPtr; }
    __syncthreads();
    if (t < NW) s_row[t] = heT[(size_t)s_invb * NW + t];
    __syncthreads();
    const bool bge = (b >= s_nr);
    for (int pass = 0; pass < 8; ++pass) {
        int a = pass * 256 + t;
        int ia = s_inv[a];
        bool bit = bge && (a < b) &&
                   (((s_row[ia >> 6] >> (ia & 63)) & 1ull) != 0);
        u64 m = __ballot(bit);
        if ((t & 63) == 0) Ap[(size_t)b * NW + (a >> 6)] = m;
    }
}

// ---------------------------------------------------------------------------
// K4 (fused diag+ap2): block (i,j), j<=i. (round-8 proven)
// ---------------------------------------------------------------------------
__global__ __launch_bounds__(64) void diagap2_kernel(
    u64* __restrict__ Ap, u64* __restrict__ Di)
{
    const int i = blockIdx.x;
    const int j = blockIdx.y;
    if (j > i) return;
    __shared__ u64 sm[64];
    const int r = threadIdx.x;
    u64 M = Ap[(size_t)(64 * i + r) * NW + i] | (1ull << r);
    for (int s = 0; s < 6; ++s) {
        sm[r] = M;
        __syncthreads();
        u64 acc = 0;
        #pragma unroll
        for (int b = 0; b < 64; ++b)
            acc |= sm[b] & (0ull - ((M >> b) & 1ull));
        __syncthreads();
        M = acc;
    }
    if (j == i) { Di[64 * i + r] = M; return; }
    sm[r] = Ap[(size_t)(64 * i + r) * NW + j];
    __syncthreads();
    u64 acc = 0;
    #pragma unroll
    for (int b = 0; b < 64; ++b)
        acc |= sm[b] & (0ull - ((M >> b) & 1ull));
    Ap[(size_t)(64 * i + r) * NW + j] = acc;
}

// ---------------------------------------------------------------------------
// K5: half-triangle forward-substitution closure (round-8 proven).
// ---------------------------------------------------------------------------
__global__ __launch_bounds__(1024) void colhalf_kernel(
    const u64* __restrict__ Ap, const u64* __restrict__ Di,
    u64* __restrict__ Anc)
{
    __shared__ __align__(16) u64 colA[16][64];
    __shared__ u64 part[16][64];
    const int t  = threadIdx.x;
    const int r  = t & 63;
    const int wv = t >> 6;
    const int k    = blockIdx.x & 15;
    const int hb   = blockIdx.x >> 4;
    const int base = hb << 4;
    const int bend = base + 16;
    const int kk   = base + k;

    for (int row = t; row < 64 * kk; row += 1024)
        Anc[(size_t)row * NW + kk] = 0ull;

    if (t < 64) {
        u64 d = Di[64 * kk + r];
        colA[0][r] = d;
        Anc[(size_t)(64 * kk + r) * NW + kk] = d;
    }
    __syncthreads();

    const int j0 = kk + wv;

    for (int ib = kk + 1; ib < bend; ib += 4) {
        u64 m0[4], acc[4];
        #pragma unroll
        for (int g = 0; g < 4; ++g) {
            int ig = ib + g;
            bool v = (ig < bend);
            m0[g] = (v && (j0 < ib)) ? Ap[(size_t)(64 * ig + r) * NW + j0] : 0ull;
            acc[g] = 0ull;
        }
        u64 tm[3][3];
        #pragma unroll
        for (int s = 0; s < 3; ++s) {
            #pragma unroll
            for (int q = 0; q < 3; ++q) {
                int g = s + 1 + q;
                tm[s][q] = (g < 4 && (ib + g) < bend)
                    ? Ap[(size_t)(64 * (ib + g) + r) * NW + (ib + s)] : 0ull;
            }
        }

        if (j0 < ib) {
            const ulonglong2* rp = (const ulonglong2*)&colA[j0 - kk][0];
            #pragma unroll
            for (int bp = 0; bp < 32; ++bp) {
                ulonglong2 ww = rp[bp];
                #pragma unroll
                for (int g = 0; g < 4; ++g)
                    acc[g] = orsel2(acc[g], ww.x, ww.y, m0[g], 2 * bp);
            }
        }

        #pragma unroll
        for (int s = 0; s < 4; ++s) {
            const int i = ib + s;
            if (i < bend) {
                part[wv][r] = acc[s];
                __syncthreads();
                if (wv < 2) {
                    u64 red = part[0][r];
                    #pragma unroll
                    for (int p = 1; p < 16; ++p) red |= part[p][r];
                    if (wv == 0) colA[i - kk][r] = red;
                    else Anc[(size_t)(64 * i + r) * NW + kk] = red;
                }
                __syncthreads();
                if (s < 3 && (i + 1) < bend) {
                    const u64* rowp = colA[i - kk];
                    #pragma unroll
                    for (int bi = 0; bi < 4; ++bi) {
                        int b = 4 * wv + bi;
                        u64 w = rowp[b];
                        u32 wl = (u32)w, wh = (u32)(w >> 32);
                        #pragma unroll
                        for (int q = 0; q < 3; ++q) {
                            int g = s + 1 + q;
                            if (g < 4) {
                                u32 sm2 = (u32)(0u - (u32)((tm[s][q] >> b) & 1ull));
                                u32 al = (u32)acc[g] | (wl & sm2);
                                u32 ah = (u32)(acc[g] >> 32) | (wh & sm2);
                                acc[g] = ((u64)ah << 32) | al;
                            }
                        }
                    }
                }
            }
        }
    }
}

// ---------------------------------------------------------------------------
// K6 (fused merges, associativity): X = (B* · C') · A*, 128 blocks x 8-row tiles.
// Stage A: Y = B*tile x C' ; Stage B: X = Y x A*. Plain stores, no atomics.
// ---------------------------------------------------------------------------
__global__ __launch_bounds__(256) void mergefused_kernel(
    const u64* __restrict__ Bstar,   // B* rows: Anc B-rows, words 16..31
    const u64* __restrict__ Cp,      // C' rows: Ap  B-rows, words 0..15
    const u64* __restrict__ Astar,   // A* rows: Anc T-rows, words 0..15
    u64* __restrict__ Out)           // Anc B-rows, words 0..15
{
    __shared__ u64 SQ[256][17];   // 34816 B
    __shared__ u64 PL[8][16];     //  1024 B
    __shared__ u64 YL[8][16];     //  1024 B
    const int t    = threadIdx.x;
    const int lane = t & 63;
    const int wv   = t >> 6;      // 0..3 (2 rows each)
    const int grp  = lane >> 4;   // 0..3 (c-phase)
    const int w    = lane & 15;
    const int rb   = blockIdx.x;  // 0..127

    if (t < 128) PL[t >> 4][t & 15] = Bstar[(size_t)(8 * rb + (t >> 4)) * NW + (t & 15)];

    u64 acc0 = 0, acc1 = 0;

    // ---- Stage A: Y = PL x C' ----
    for (int cs = 0; cs < 4; ++cs) {
        __syncthreads();
        for (int q = t; q < 4096; q += 256)
            SQ[q >> 4][q & 15] = Cp[(size_t)(256 * cs + (q >> 4)) * NW + (q & 15)];
        __syncthreads();
        #pragma unroll
        for (int cw = 0; cw < 4; ++cw) {
            u64 m0 = PL[2 * wv + 0][cs * 4 + cw];
            u64 m1 = PL[2 * wv + 1][cs * 4 + cw];
            #pragma unroll
            for (int cc = 0; cc < 16; ++cc) {
                u64 qq = SQ[cw * 64 + cc * 4 + grp][w];
                int sh = (cc & 7) * 4 + grp;
                u32 h0 = (cc < 8) ? (u32)m0 : (u32)(m0 >> 32);
                u32 h1 = (cc < 8) ? (u32)m1 : (u32)(m1 >> 32);
                u32 ql = (u32)qq, qh = (u32)(qq >> 32);
                u32 s;
                s = SBFE(h0, sh);
                acc0 = ((u64)(((u32)(acc0 >> 32)) | (qh & s)) << 32) | (((u32)acc0) | (ql & s));
                s = SBFE(h1, sh);
                acc1 = ((u64)(((u32)(acc1 >> 32)) | (qh & s)) << 32) | (((u32)acc1) | (ql & s));
            }
        }
    }
    acc0 |= __shfl_xor(acc0, 16); acc0 |= __shfl_xor(acc0, 32);
    acc1 |= __shfl_xor(acc1, 16); acc1 |= __shfl_xor(acc1, 32);
    if (grp == 0) { YL[2 * wv + 0][w] = acc0; YL[2 * wv + 1][w] = acc1; }
    __syncthreads();   // all stage-A SQ reads done; YL visible

    // ---- Stage B: X = YL x A* ----
    acc0 = 0; acc1 = 0;
    for (int cs = 0; cs < 4; ++cs) {
        __syncthreads();
        for (int q = t; q < 4096; q += 256)
            SQ[q >> 4][q & 15] = Astar[(size_t)(256 * cs + (q >> 4)) * NW + (q & 15)];
        __syncthreads();
        #pragma unroll
        for (int cw = 0; cw < 4; ++cw) {
            u64 m0 = YL[2 * wv + 0][cs * 4 + cw];
            u64 m1 = YL[2 * wv + 1][cs * 4 + cw];
            #pragma unroll
            for (int cc = 0; cc < 16; ++cc) {
                u64 qq = SQ[cw * 64 + cc * 4 + grp][w];
                int sh = (cc & 7) * 4 + grp;
                u32 h0 = (cc < 8) ? (u32)m0 : (u32)(m0 >> 32);
                u32 h1 = (cc < 8) ? (u32)m1 : (u32)(m1 >> 32);
                u32 ql = (u32)qq, qh = (u32)(qq >> 32);
                u32 s;
                s = SBFE(h0, sh);
                acc0 = ((u64)(((u32)(acc0 >> 32)) | (qh & s)) << 32) | (((u32)acc0) | (ql & s));
                s = SBFE(h1, sh);
                acc1 = ((u64)(((u32)(acc1 >> 32)) | (qh & s)) << 32) | (((u32)acc1) | (ql & s));
            }
        }
    }
    acc0 |= __shfl_xor(acc0, 16); acc0 |= __shfl_xor(acc0, 32);
    acc1 |= __shfl_xor(acc1, 16); acc1 |= __shfl_xor(acc1, 32);
    if (grp == 0) {
        size_t base = (size_t)(8 * rb + 2 * wv) * NW + w;
        Out[base] = acc0;
        Out[base + NW] = acc1;
    }
}

// ---------------------------------------------------------------------------
// K7 (fused fold+out): dag[i][j] = he & !root_j & !anc & reach_i (round-8 proven)
// ---------------------------------------------------------------------------
__global__ __launch_bounds__(256) void foldout_kernel(
    const u64* __restrict__ heBits,
    const u64* __restrict__ Anc,
    const u16* __restrict__ posr,
    float* __restrict__ dag)
{
    __shared__ u64 s_anc[NW];
    __shared__ u64 s_he[NW];
    __shared__ u16 s_pr[NN];
    const int i = blockIdx.x;
    const int t = threadIdx.x;

    ((int4*)s_pr)[t] = ((const int4*)posr)[t];
    __syncthreads();
    const int fl = s_pr[i];
    const int pi = fl & 0x7FF;
    if (t < NW) {
        s_anc[t] = Anc[(size_t)pi * NW + t];
        s_he[t]  = heBits[(size_t)i * NW + t];
    }
    __syncthreads();
    const bool reach_i = (fl & 0x4000) != 0;
    const int j0 = t * 8;
    float o[8];
    #pragma unroll
    for (int e = 0; e < 8; ++e) {
        int j = j0 + e;
        int pr = s_pr[j];
        int a = pr & 0x7FF;
        bool he = ((s_he[j >> 6] >> (j & 63)) & 1ull) != 0;
        bool anc = ((s_anc[a >> 6] >> (a & 63)) & 1ull) != 0;
        o[e] = (reach_i && he && ((pr & 0x8000) == 0) && !anc) ? 1.f : 0.f;
    }
    float4* outp = (float4*)(dag + (size_t)i * NN + j0);
    outp[0] = make_float4(o[0], o[1], o[2], o[3]);
    outp[1] = make_float4(o[4], o[5], o[6], o[7]);
}

// ---------------------------------------------------------------------------
extern "C" void kernel_launch(void* const* d_in, const int* in_sizes, int n_in,
                              void* d_out, int out_size, void* d_ws, size_t ws_size,
                              hipStream_t stream) {
    const float* root_logits = (const float*)d_in[0];
    const float* edge_logits = (const float*)d_in[1];
    const float* g_root      = (const float*)d_in[2];
    const float* g_edge      = (const float*)d_in[3];
    float* dag = (float*)d_out;

    char* ws = (char*)d_ws;
    u64* heBits  = (u64*)(ws);                            // 512 KB
    u64* heT     = (u64*)(ws + (512 << 10));              // 512 KB
    u64* Ap      = (u64*)(ws + (1 << 20));                // 512 KB
    u64* Anc     = (u64*)(ws + (1 << 20) + (512 << 10));  // 512 KB
    u64* Di      = (u64*)(ws + (2 << 20));                //  16 KB
    u16* posr    = (u16*)(ws + (2 << 20) + (192 << 10));  //   4 KB
    u16* porderW = (u16*)(ws + (2 << 20) + (196 << 10));  //   4 KB
    int* nrPtr   = (int*)(ws + (2 << 20) + (200 << 10));  //   4 B

    prep_kernel    <<<NN, 256, 0, stream>>>(edge_logits, g_edge, heBits);
    ordtrans_kernel<<<256, 1024, 0, stream>>>(root_logits, g_root, heBits, heT,
                                              posr, porderW, nrPtr);
    apbuild_kernel <<<NN, 256, 0, stream>>>(heT, porderW, nrPtr, Ap);
    diagap2_kernel <<<dim3(NW, NW), 64, 0, stream>>>(Ap, Di);
    colhalf_kernel <<<NW, 1024, 0, stream>>>(Ap, Di, Anc);
    mergefused_kernel<<<128, 256, 0, stream>>>(Anc + (size_t)1024 * NW + 16,
                                               Ap + (size_t)1024 * NW,
                                               Anc,
                                               Anc + (size_t)1024 * NW);
    foldout_kernel <<<NN, 256, 0, stream>>>(heBits, Anc, posr, dag);
}

// Round 11
// 127.230 us; speedup vs baseline: 3.6146x; 1.2140x over previous
//
#include <hip/hip_runtime.h>
#include <stdint.h>

typedef unsigned long long u64;
typedef unsigned int u32;
typedef unsigned short u16;

#define NN 2048
#define NW 32    // u64 words per 2048-bit row

#if __has_builtin(__builtin_amdgcn_sbfe)
#define SBFE(x, o) ((u32)__builtin_amdgcn_sbfe((int)(x), (u32)(o), 1u))
#else
#define SBFE(x, o) ((u32)(-(int)(((x) >> (o)) & 1u)))
#endif

static __device__ __forceinline__ bool gumbel_gt(float x, float g0, float g1) {
    // jax.nn.log_sigmoid(x) = -(max(-x,0) + log1p(exp(-|x|)))
    float L = log1pf(expf(-fabsf(x)));
    float a = (-(fmaxf(-x, 0.f) + L)) + g0;   // ye[0]
    float b = (-(fmaxf( x, 0.f) + L)) + g1;   // ye[1]
    return a > b;
}

// acc |= (bit b0 of m ? w0 : 0) | (bit b0+1 of m ? w1 : 0); b0 even, compile-time
static __device__ __forceinline__ u64 orsel2(u64 acc, u64 w0, u64 w1, u64 m, int b0) {
    u32 mm = (b0 < 32) ? (u32)m : (u32)(m >> 32);
    int sh = b0 & 31;
    u32 s0 = SBFE(mm, sh);
    u32 s1 = SBFE(mm, sh + 1);
    u32 al = (u32)acc | ((u32)w0 & s0) | ((u32)w1 & s1);
    u32 ah = (u32)(acc >> 32) | ((u32)(w0 >> 32) & s0) | ((u32)(w1 >> 32) & s1);
    return ((u64)ah << 32) | al;
}

// ---------------------------------------------------------------------------
// K1: hard-edge bitmask  he[i][j]  (proven)
// ---------------------------------------------------------------------------
__global__ __launch_bounds__(256) void prep_kernel(
    const float* __restrict__ edge_logits,
    const float* __restrict__ g_edge,
    u64* __restrict__ heBits)
{
    const int i = blockIdx.x;
    const int t = threadIdx.x;
    const int lane = t & 63;
    const int wave = t >> 6;
    for (int c = wave; c < NW; c += 4) {
        int j = (c << 6) + lane;
        float x  = edge_logits[(size_t)i * NN + j];
        float g0 = g_edge[(size_t)i * (2 * NN) + j];
        float g1 = g_edge[(size_t)i * (2 * NN) + NN + j];
        u64 m = __ballot(gumbel_gt(x, g0, g1));
        if (lane == 0) heBits[(size_t)i * NW + c] = m;
    }
}

// ---------------------------------------------------------------------------
// order body (proven)
// ---------------------------------------------------------------------------
static __device__ void order_body(char* smem,
    const float* __restrict__ root_logits, const float* __restrict__ g_root,
    const u64* __restrict__ heBits,
    u16* __restrict__ posr, u16* __restrict__ porderW, int* __restrict__ nrPtr)
{
    int* s_porder = (int*)smem;                    // 8192
    int* s_cnt    = (int*)(smem + 8192);           // 8192
    u64 (*s_U)[NW]  = (u64(*)[NW])(smem + 16384);  // 4096
    u64 (*s_Pg)[NW] = (u64(*)[NW])(smem + 20480);  // 4096
    u16* s_pos = (u16*)(smem + 24576);             // 4096
    u16* s_f   = (u16*)(smem + 28672);             // 4096
    u16* s_rk  = (u16*)(smem + 32768);             // 4096
    u64* s_root = (u64*)(smem + 36864);            // 256
    u64* s_enq  = (u64*)(smem + 37120);            // 256
    u64* s_F    = (u64*)(smem + 37376);            // 256
    int* s_wsum = (int*)(smem + 37632);            // 64
    int* s_woff = (int*)(smem + 37696);            // 64
    int* s_sc   = (int*)(smem + 37760);            // scalars
    int &s_base = s_sc[0]; int &s_lo = s_sc[1]; int &s_levcnt = s_sc[2];
    int &s_newcnt = s_sc[3]; int &s_nr = s_sc[4];

    const int t    = threadIdx.x;
    const int lane = t & 63;
    const int wid  = t >> 6;
    const int half = lane >> 5;
    const int w    = lane & 31;

    for (int p = 0; p < 2; ++p) {
        int j = p * 1024 + t;
        bool rb = gumbel_gt(root_logits[j], g_root[j], g_root[NN + j]);
        u64 m = __ballot(rb);
        if (lane == 0) s_root[j >> 6] = m;
    }
    __syncthreads();
    for (int p = 0; p < 2; ++p) {
        int j = p * 1024 + t;
        int ww = j >> 6; u64 bit = 1ull << (j & 63);
        if (s_root[ww] & bit) {
            int r = 0;
            for (int k = 0; k < ww; ++k) r += __popcll(s_root[k]);
            r += __popcll(s_root[ww] & (bit - 1ull));
            s_pos[j] = (u16)r;
            s_porder[r] = j;
        }
    }
    if (t < NW) s_enq[t] = s_root[t];
    if (t == 0) {
        int tl = 0;
        for (int k = 0; k < NW; ++k) tl += __popcll(s_root[k]);
        s_lo = 0; s_levcnt = tl; s_base = tl; s_nr = tl;
    }
    __syncthreads();

    while (s_levcnt > 0 && s_base < NN) {
        const int lo = s_lo, cnt = s_levcnt, base = s_base;
        const int seglen = (cnt + 15) >> 4;
        const int s0 = wid * seglen;
        const int s1 = (s0 + seglen < cnt) ? (s0 + seglen) : cnt;

        {
            u64 acc = 0;
            for (int m = s0 + half; m < s1; m += 2)
                acc |= heBits[(size_t)s_porder[lo + m] * NW + w];
            acc |= __shfl(acc, lane ^ 32);
            if (half == 0) s_U[wid][w] = acc;
        }
        __syncthreads();
        if (t < NW) {
            u64 o = 0;
            #pragma unroll
            for (int s = 0; s < 16; ++s) o |= s_U[s][t];
            s_F[t] = o & ~s_enq[t] & ~s_root[t];
        }
        __syncthreads();
        if (t < 512) {
            int s = t >> 5, ww = t & 31;
            u64 p = 0;
            for (int s2 = 0; s2 < s; ++s2) p |= s_U[s2][ww];
            s_Pg[s][ww] = p & s_F[ww];
        }
        __syncthreads();
        {
            u64 P  = s_Pg[wid][w];
            u64 Fw = s_F[w];
            int myidx = (s0 + lane < s1) ? s_porder[lo + s0 + lane] : 0;
            u64 rnext = 0;
            {
                int rowi0 = __shfl(myidx, half);
                if (s0 + half < s1) rnext = heBits[(size_t)rowi0 * NW + w];
            }
            for (int m = s0; m < s1; m += 2) {
                int m0 = m + half;
                u64 r = rnext;
                {
                    int sidx = (m + 2 - s0) + half;
                    if (sidx > 63) sidx = 0;
                    int rowin = __shfl(myidx, sidx);
                    rnext = 0;
                    if (m + 2 + half < s1) rnext = heBits[(size_t)rowin * NW + w];
                }
                u64 v = (m0 < s1) ? (r & Fw & ~P) : 0ull;
                u64 vlo = __shfl(v, w);
                u64 B = half ? (v & ~vlo) : v;
                int pc = __popcll(B);
                int inc = pc;
                #pragma unroll
                for (int d = 1; d < 32; d <<= 1) {
                    int u2 = __shfl_up(inc, d, 64);
                    if (w >= d) inc += u2;
                }
                int excl = inc - pc;
                int tot = __shfl(inc, (half << 5) | 31);
                if (w == 0 && m0 < s1) s_cnt[m0] = tot;
                u64 mm = B;
                int idx = excl;
                while (mm) {
                    int b = __ffsll(mm) - 1; mm &= mm - 1;
                    int j = (w << 6) + b;
                    s_f[j]  = (u16)m0;
                    s_rk[j] = (u16)idx++;
                }
                P |= B | __shfl(B, lane ^ 32);
            }
        }
        __syncthreads();
        {
            int b0 = 2 * t, b1 = 2 * t + 1;
            int c0 = (b0 < cnt) ? s_cnt[b0] : 0;
            int c1 = (b1 < cnt) ? s_cnt[b1] : 0;
            int pairv = c0 + c1;
            int incl = pairv;
            for (int d = 1; d < 64; d <<= 1) {
                int v = __shfl_up(incl, d, 64);
                if (lane >= d) incl += v;
            }
            if (lane == 63) s_wsum[wid] = incl;
            __syncthreads();
            if (t < 16) {
                int v = s_wsum[t];
                int inc2 = v;
                for (int d = 1; d < 16; d <<= 1) {
                    int u = __shfl_up(inc2, d, 16);
                    if (t >= d) inc2 += u;
                }
                s_woff[t] = inc2 - v;
                if (t == 15) s_newcnt = inc2;
            }
            __syncthreads();
            int excl = s_woff[wid] + (incl - pairv);
            if (b0 < cnt) s_cnt[b0] = excl;
            if (b1 < cnt) s_cnt[b1] = excl + c0;
        }
        __syncthreads();
        for (int p = 0; p < 2; ++p) {
            int j = p * 1024 + t;
            int ww = j >> 6;
            if ((s_F[ww] >> (j & 63)) & 1ull) {
                int slot = base + s_cnt[s_f[j]] + s_rk[j];
                s_pos[j] = (u16)slot;
                s_porder[slot] = j;
            }
        }
        if (t < NW) s_enq[t] |= s_F[t];
        __syncthreads();
        if (t == 0) { s_lo = base; s_levcnt = s_newcnt; s_base = base + s_newcnt; }
        __syncthreads();
    }

    for (int p = 0; p < 2; ++p) {
        int j = p * 1024 + t;
        int ww = j >> 6; u64 bit = 1ull << (j & 63);
        if (!((s_enq[ww] >> (j & 63)) & 1ull)) {
            int rk = 0;
            for (int k2 = 0; k2 < ww; ++k2) rk += __popcll(~s_enq[k2]);
            rk += __popcll(~s_enq[ww] & (bit - 1ull));
            int slot = s_base + rk;
            s_pos[j] = (u16)slot;
            s_porder[slot] = j;
        }
    }
    __syncthreads();
    for (int p = 0; p < 2; ++p) {
        int j = p * 1024 + t;
        int fl = s_pos[j];
        if ((s_root[j >> 6] >> (j & 63)) & 1ull) fl |= 0x8000;
        if ((s_enq[j >> 6]  >> (j & 63)) & 1ull) fl |= 0x4000;
        posr[j] = (u16)fl;
        porderW[j] = (u16)s_porder[j];
    }
    if (t == 0) *nrPtr = s_nr;
}

// ---------------------------------------------------------------------------
// K2 (fused): block 0 = order; blocks 1..255 = bit-transpose (proven)
// ---------------------------------------------------------------------------
__global__ __launch_bounds__(1024) void ordtrans_kernel(
    const float* __restrict__ root_logits,
    const float* __restrict__ g_root,
    const u64* __restrict__ heBits,
    u64* __restrict__ heT,
    u16* __restrict__ posr,
    u16* __restrict__ porderW,
    int* __restrict__ nrPtr)
{
    __shared__ __align__(16) char smem[38016];
    const int bid  = blockIdx.x;
    const int t    = threadIdx.x;
    const int lane = t & 63;
    const int wv   = t >> 6;

    if (bid == 0) {
        order_body(smem, root_logits, g_root, heBits, posr, porderW, nrPtr);
    } else {
        int gw = (bid - 1) * 16 + wv;
        if (gw < 1024) {
            int ti = gw >> 5, tj = gw & 31;
            u64 w = heBits[(size_t)(64 * ti + lane) * NW + tj];
            u64 out = 0;
            #pragma unroll
            for (int b = 0; b < 64; ++b) {
                u64 m = __ballot(((w >> b) & 1ull) != 0);
                if (b == lane) out = m;
            }
            heT[(size_t)(64 * tj + lane) * NW + ti] = out;
        }
    }
}

// ---------------------------------------------------------------------------
// K3: permuted strict-lower parent matrix (proven)
// ---------------------------------------------------------------------------
__global__ __launch_bounds__(256) void apbuild_kernel(
    const u64* __restrict__ heT, const u16* __restrict__ porderW,
    const int* __restrict__ nrPtr, u64* __restrict__ Ap)
{
    __shared__ u64 s_row[NW];
    __shared__ u16 s_inv[NN];
    __shared__ int s_invb, s_nr;
    const int b = blockIdx.x;
    const int t = threadIdx.x;
    for (int q = t; q < NN; q += 256) s_inv[q] = porderW[q];
    if (t == 0) { s_invb = porderW[b]; s_nr = *nrPtr; }
    __syncthreads();
    if (t < NW) s_row[t] = heT[(size_t)s_invb * NW + t];
    __syncthreads();
    const bool bge = (b >= s_nr);
    for (int pass = 0; pass < 8; ++pass) {
        int a = pass * 256 + t;
        int ia = s_inv[a];
        bool bit = bge && (a < b) &&
                   (((s_row[ia >> 6] >> (ia & 63)) & 1ull) != 0);
        u64 m = __ballot(bit);
        if ((t & 63) == 0) Ap[(size_t)b * NW + (a >> 6)] = m;
    }
}

// ---------------------------------------------------------------------------
// K4 (fused diag+ap2): block (i,j), j<=i. (proven)
// ---------------------------------------------------------------------------
__global__ __launch_bounds__(64) void diagap2_kernel(
    u64* __restrict__ Ap, u64* __restrict__ Di)
{
    const int i = blockIdx.x;
    const int j = blockIdx.y;
    if (j > i) return;
    __shared__ u64 sm[64];
    const int r = threadIdx.x;
    u64 M = Ap[(size_t)(64 * i + r) * NW + i] | (1ull << r);
    for (int s = 0; s < 6; ++s) {
        sm[r] = M;
        __syncthreads();
        u64 acc = 0;
        #pragma unroll
        for (int b = 0; b < 64; ++b)
            acc |= sm[b] & (0ull - ((M >> b) & 1ull));
        __syncthreads();
        M = acc;
    }
    if (j == i) { Di[64 * i + r] = M; return; }
    sm[r] = Ap[(size_t)(64 * i + r) * NW + j];
    __syncthreads();
    u64 acc = 0;
    #pragma unroll
    for (int b = 0; b < 64; ++b)
        acc |= sm[b] & (0ull - ((M >> b) & 1ull));
    Ap[(size_t)(64 * i + r) * NW + j] = acc;
}

// ---------------------------------------------------------------------------
// K5: half-triangle forward-substitution closure (proven).
// ---------------------------------------------------------------------------
__global__ __launch_bounds__(1024) void colhalf_kernel(
    const u64* __restrict__ Ap, const u64* __restrict__ Di,
    u64* __restrict__ Anc)
{
    __shared__ __align__(16) u64 colA[16][64];
    __shared__ u64 part[16][64];
    const int t  = threadIdx.x;
    const int r  = t & 63;
    const int wv = t >> 6;
    const int k    = blockIdx.x & 15;
    const int hb   = blockIdx.x >> 4;
    const int base = hb << 4;
    const int bend = base + 16;
    const int kk   = base + k;

    for (int row = t; row < 64 * kk; row += 1024)
        Anc[(size_t)row * NW + kk] = 0ull;

    if (t < 64) {
        u64 d = Di[64 * kk + r];
        colA[0][r] = d;
        Anc[(size_t)(64 * kk + r) * NW + kk] = d;
    }
    __syncthreads();

    const int j0 = kk + wv;

    for (int ib = kk + 1; ib < bend; ib += 4) {
        u64 m0[4], acc[4];
        #pragma unroll
        for (int g = 0; g < 4; ++g) {
            int ig = ib + g;
            bool v = (ig < bend);
            m0[g] = (v && (j0 < ib)) ? Ap[(size_t)(64 * ig + r) * NW + j0] : 0ull;
            acc[g] = 0ull;
        }
        u64 tm[3][3];
        #pragma unroll
        for (int s = 0; s < 3; ++s) {
            #pragma unroll
            for (int q = 0; q < 3; ++q) {
                int g = s + 1 + q;
                tm[s][q] = (g < 4 && (ib + g) < bend)
                    ? Ap[(size_t)(64 * (ib + g) + r) * NW + (ib + s)] : 0ull;
            }
        }

        if (j0 < ib) {
            const ulonglong2* rp = (const ulonglong2*)&colA[j0 - kk][0];
            #pragma unroll
            for (int bp = 0; bp < 32; ++bp) {
                ulonglong2 ww = rp[bp];
                #pragma unroll
                for (int g = 0; g < 4; ++g)
                    acc[g] = orsel2(acc[g], ww.x, ww.y, m0[g], 2 * bp);
            }
        }

        #pragma unroll
        for (int s = 0; s < 4; ++s) {
            const int i = ib + s;
            if (i < bend) {
                part[wv][r] = acc[s];
                __syncthreads();
                if (wv < 2) {
                    u64 red = part[0][r];
                    #pragma unroll
                    for (int p = 1; p < 16; ++p) red |= part[p][r];
                    if (wv == 0) colA[i - kk][r] = red;
                    else Anc[(size_t)(64 * i + r) * NW + kk] = red;
                }
                __syncthreads();
                if (s < 3 && (i + 1) < bend) {
                    const u64* rowp = colA[i - kk];
                    #pragma unroll
                    for (int bi = 0; bi < 4; ++bi) {
                        int b = 4 * wv + bi;
                        u64 w = rowp[b];
                        u32 wl = (u32)w, wh = (u32)(w >> 32);
                        #pragma unroll
                        for (int q = 0; q < 3; ++q) {
                            int g = s + 1 + q;
                            if (g < 4) {
                                u32 sm2 = (u32)(0u - (u32)((tm[s][q] >> b) & 1ull));
                                u32 al = (u32)acc[g] | (wl & sm2);
                                u32 ah = (u32)(acc[g] >> 32) | (wh & sm2);
                                acc[g] = ((u64)ah << 32) | al;
                            }
                        }
                    }
                }
            }
        }
    }
}

// ---------------------------------------------------------------------------
// K6a: merge stage 1, c-split partials: Yp[q] = B*(words 16+4q..) x C'(rows 256q..)
// grid (128 row-tiles x 4 c-slices), 256 thr. Plain stores, no atomics.
// ---------------------------------------------------------------------------
__global__ __launch_bounds__(256) void merge1_kernel(
    const u64* __restrict__ Bstar,   // Anc B-rows base (stride NW)
    const u64* __restrict__ CpRows,  // Ap B-rows base (stride NW), words 0..15
    u64* __restrict__ Yp)            // [4][1024][16]
{
    __shared__ u64 SQ[256][17];
    __shared__ u64 PL[8][4];
    const int t    = threadIdx.x;
    const int lane = t & 63;
    const int wv   = t >> 6;
    const int grp  = lane >> 4;
    const int w    = lane & 15;
    const int rb   = blockIdx.x;   // 0..127
    const int q    = blockIdx.y;   // 0..3

    if (t < 32)
        PL[t >> 2][t & 3] = Bstar[(size_t)(8 * rb + (t >> 2)) * NW + 16 + 4 * q + (t & 3)];
    for (int s = t; s < 4096; s += 256)
        SQ[s >> 4][s & 15] = CpRows[(size_t)(256 * q + (s >> 4)) * NW + (s & 15)];
    __syncthreads();

    u64 acc0 = 0, acc1 = 0;
    #pragma unroll
    for (int cw = 0; cw < 4; ++cw) {
        u64 m0 = PL[2 * wv + 0][cw];
        u64 m1 = PL[2 * wv + 1][cw];
        #pragma unroll
        for (int cc = 0; cc < 16; ++cc) {
            u64 qq = SQ[cw * 64 + cc * 4 + grp][w];
            int sh = (cc & 7) * 4 + grp;
            u32 h0 = (cc < 8) ? (u32)m0 : (u32)(m0 >> 32);
            u32 h1 = (cc < 8) ? (u32)m1 : (u32)(m1 >> 32);
            u32 ql = (u32)qq, qh = (u32)(qq >> 32);
            u32 s;
            s = SBFE(h0, sh);
            acc0 = ((u64)(((u32)(acc0 >> 32)) | (qh & s)) << 32) | (((u32)acc0) | (ql & s));
            s = SBFE(h1, sh);
            acc1 = ((u64)(((u32)(acc1 >> 32)) | (qh & s)) << 32) | (((u32)acc1) | (ql & s));
        }
    }
    acc0 |= __shfl_xor(acc0, 16); acc0 |= __shfl_xor(acc0, 32);
    acc1 |= __shfl_xor(acc1, 16); acc1 |= __shfl_xor(acc1, 32);
    if (grp == 0) {
        size_t base = ((size_t)q * 1024 + 8 * rb + 2 * wv) * 16 + w;
        Yp[base] = acc0;
        Yp[base + 16] = acc1;
    }
}

// ---------------------------------------------------------------------------
// K6b: merge stage 2: Xp[q] = (OR_q' Yp[q'])(words 4q..) x A*(rows 256q..)
// ---------------------------------------------------------------------------
__global__ __launch_bounds__(256) void merge2_kernel(
    const u64* __restrict__ Yp,      // [4][1024][16]
    const u64* __restrict__ Astar,   // Anc T-rows (stride NW), words 0..15
    u64* __restrict__ Xp)            // [4][1024][16]
{
    __shared__ u64 SQ[256][17];
    __shared__ u64 PL[8][4];
    const int t    = threadIdx.x;
    const int lane = t & 63;
    const int wv   = t >> 6;
    const int grp  = lane >> 4;
    const int w    = lane & 15;
    const int rb   = blockIdx.x;
    const int q    = blockIdx.y;

    if (t < 32) {
        size_t idx = (size_t)(8 * rb + (t >> 2)) * 16 + 4 * q + (t & 3);
        PL[t >> 2][t & 3] = Yp[idx] | Yp[idx + 16384] | Yp[idx + 32768] | Yp[idx + 49152];
    }
    for (int s = t; s < 4096; s += 256)
        SQ[s >> 4][s & 15] = Astar[(size_t)(256 * q + (s >> 4)) * NW + (s & 15)];
    __syncthreads();

    u64 acc0 = 0, acc1 = 0;
    #pragma unroll
    for (int cw = 0; cw < 4; ++cw) {
        u64 m0 = PL[2 * wv + 0][cw];
        u64 m1 = PL[2 * wv + 1][cw];
        #pragma unroll
        for (int cc = 0; cc < 16; ++cc) {
            u64 qq = SQ[cw * 64 + cc * 4 + grp][w];
            int sh = (cc & 7) * 4 + grp;
            u32 h0 = (cc < 8) ? (u32)m0 : (u32)(m0 >> 32);
            u32 h1 = (cc < 8) ? (u32)m1 : (u32)(m1 >> 32);
            u32 ql = (u32)qq, qh = (u32)(qq >> 32);
            u32 s;
            s = SBFE(h0, sh);
            acc0 = ((u64)(((u32)(acc0 >> 32)) | (qh & s)) << 32) | (((u32)acc0) | (ql & s));
            s = SBFE(h1, sh);
            acc1 = ((u64)(((u32)(acc1 >> 32)) | (qh & s)) << 32) | (((u32)acc1) | (ql & s));
        }
    }
    acc0 |= __shfl_xor(acc0, 16); acc0 |= __shfl_xor(acc0, 32);
    acc1 |= __shfl_xor(acc1, 16); acc1 |= __shfl_xor(acc1, 32);
    if (grp == 0) {
        size_t base = ((size_t)q * 1024 + 8 * rb + 2 * wv) * 16 + w;
        Xp[base] = acc0;
        Xp[base + 16] = acc1;
    }
}

// ---------------------------------------------------------------------------
// K7 (fold+out): dag[i][j] = he & !root_j & !anc & reach_i; B-row anc words
// 0..15 come from OR of the 4 Xp partials.
// ---------------------------------------------------------------------------
__global__ __launch_bounds__(256) void foldout_kernel(
    const u64* __restrict__ heBits,
    const u64* __restrict__ Anc,
    const u64* __restrict__ Xp,      // [4][1024][16]
    const u16* __restrict__ posr,
    float* __restrict__ dag)
{
    __shared__ u64 s_anc[NW];
    __shared__ u64 s_he[NW];
    __shared__ u16 s_pr[NN];
    const int i = blockIdx.x;
    const int t = threadIdx.x;

    ((int4*)s_pr)[t] = ((const int4*)posr)[t];
    __syncthreads();
    const int fl = s_pr[i];
    const int pi = fl & 0x7FF;
    if (t < NW) {
        u64 v;
        if (pi >= 1024 && t < 16) {
            size_t idx = (size_t)(pi - 1024) * 16 + t;
            v = Xp[idx] | Xp[idx + 16384] | Xp[idx + 32768] | Xp[idx + 49152];
        } else {
            v = Anc[(size_t)pi * NW + t];
        }
        s_anc[t] = v;
        s_he[t]  = heBits[(size_t)i * NW + t];
    }
    __syncthreads();
    const bool reach_i = (fl & 0x4000) != 0;
    const int j0 = t * 8;
    float o[8];
    #pragma unroll
    for (int e = 0; e < 8; ++e) {
        int j = j0 + e;
        int pr = s_pr[j];
        int a = pr & 0x7FF;
        bool he = ((s_he[j >> 6] >> (j & 63)) & 1ull) != 0;
        bool anc = ((s_anc[a >> 6] >> (a & 63)) & 1ull) != 0;
        o[e] = (reach_i && he && ((pr & 0x8000) == 0) && !anc) ? 1.f : 0.f;
    }
    float4* outp = (float4*)(dag + (size_t)i * NN + j0);
    outp[0] = make_float4(o[0], o[1], o[2], o[3]);
    outp[1] = make_float4(o[4], o[5], o[6], o[7]);
}

// ---------------------------------------------------------------------------
extern "C" void kernel_launch(void* const* d_in, const int* in_sizes, int n_in,
                              void* d_out, int out_size, void* d_ws, size_t ws_size,
                              hipStream_t stream) {
    const float* root_logits = (const float*)d_in[0];
    const float* edge_logits = (const float*)d_in[1];
    const float* g_root      = (const float*)d_in[2];
    const float* g_edge      = (const float*)d_in[3];
    float* dag = (float*)d_out;

    char* ws = (char*)d_ws;
    u64* heBits  = (u64*)(ws);                            // 512 KB
    u64* heT     = (u64*)(ws + (512 << 10));              // 512 KB
    u64* Ap      = (u64*)(ws + (1 << 20));                // 512 KB
    u64* Anc     = (u64*)(ws + (1 << 20) + (512 << 10));  // 512 KB
    u64* Di      = (u64*)(ws + (2 << 20));                //  16 KB
    u16* posr    = (u16*)(ws + (2 << 20) + (192 << 10));  //   4 KB
    u16* porderW = (u16*)(ws + (2 << 20) + (196 << 10));  //   4 KB
    int* nrPtr   = (int*)(ws + (2 << 20) + (200 << 10));  //   4 B
    u64* Yp      = (u64*)(ws + (3 << 20));                // 512 KB
    u64* Xp      = (u64*)(ws + (3 << 20) + (512 << 10));  // 512 KB

    prep_kernel    <<<NN, 256, 0, stream>>>(edge_logits, g_edge, heBits);
    ordtrans_kernel<<<256, 1024, 0, stream>>>(root_logits, g_root, heBits, heT,
                                              posr, porderW, nrPtr);
    apbuild_kernel <<<NN, 256, 0, stream>>>(heT, porderW, nrPtr, Ap);
    diagap2_kernel <<<dim3(NW, NW), 64, 0, stream>>>(Ap, Di);
    colhalf_kernel <<<NW, 1024, 0, stream>>>(Ap, Di, Anc);
    merge1_kernel  <<<dim3(128, 4), 256, 0, stream>>>(Anc + (size_t)1024 * NW,
                                                      Ap + (size_t)1024 * NW, Yp);
    merge2_kernel  <<<dim3(128, 4), 256, 0, stream>>>(Yp, Anc, Xp);
    foldout_kernel <<<NN, 256, 0, stream>>>(heBits, Anc, Xp, posr, dag);
}